// Round 2
// baseline (856.686 us; speedup 1.0000x reference)
//
#include <hip/hip_runtime.h>
#include <math.h>

#define HDIM 768
#define RDIM 64
#define NEXP 8
#define NTOK 16384

__device__ __forceinline__ float gelu_exact(float v) {
    return 0.5f * v * (1.0f + erff(v * 0.70710678118654752440f));
}

// ---------------------------------------------------------------------------
// Router: 32-token tile per block (512 blocks). xenc = x@enc_w+enc_b (K=768),
// epilogue over all 256 threads (32 tok x 8 exp), shuffle argmax/softmax,
// block-aggregated routing atomics.
// ---------------------------------------------------------------------------
__global__ __launch_bounds__(256) void router_kernel(
    const float* __restrict__ x, const float* __restrict__ enc_w,
    const float* __restrict__ enc_b, const float* __restrict__ sw_w,
    const float* __restrict__ sw_b, float* __restrict__ pmax,
    int* __restrict__ counts, int* __restrict__ lists)
{
    __shared__ __align__(16) float xa[32][68];
    __shared__ __align__(16) float wb[64][68];
    __shared__ __align__(16) float sws[512];    // sw_w [64][8]
    __shared__ int lcnt[NEXP], gbase[NEXP];

    const int tid = threadIdx.x;
    const int tok0 = blockIdx.x * 32;
    const int ty = tid >> 4, tx = tid & 15, tx4 = tx * 4;

    if (tid < 128) ((float4*)sws)[tid] = ((const float4*)sw_w)[tid];
    if (tid < NEXP) lcnt[tid] = 0;

    float acc[2][4] = {};

    for (int k0 = 0; k0 < HDIM; k0 += 64) {
        #pragma unroll
        for (int it = 0; it < 2; it++) {
            int idx = it * 256 + tid;
            int r = idx >> 4, c4 = (idx & 15) * 4;
            *(float4*)&xa[r][c4] = *(const float4*)(x + (size_t)(tok0 + r) * HDIM + k0 + c4);
        }
        #pragma unroll
        for (int it = 0; it < 4; it++) {
            int off = it * 1024 + tid * 4;
            *(float4*)&wb[off >> 6][off & 63] = *(const float4*)(enc_w + (size_t)k0 * RDIM + off);
        }
        __syncthreads();
        #pragma unroll
        for (int kk = 0; kk < 64; kk += 4) {
            float4 a0 = *(float4*)&xa[ty][kk];
            float4 a1 = *(float4*)&xa[ty + 16][kk];
            float4 w[4];
            #pragma unroll
            for (int j = 0; j < 4; j++) w[j] = *(float4*)&wb[kk + j][tx4];
            float a0v[4] = {a0.x, a0.y, a0.z, a0.w};
            float a1v[4] = {a1.x, a1.y, a1.z, a1.w};
            #pragma unroll
            for (int j = 0; j < 4; j++) {
                acc[0][0] += a0v[j] * w[j].x; acc[0][1] += a0v[j] * w[j].y;
                acc[0][2] += a0v[j] * w[j].z; acc[0][3] += a0v[j] * w[j].w;
                acc[1][0] += a1v[j] * w[j].x; acc[1][1] += a1v[j] * w[j].y;
                acc[1][2] += a1v[j] * w[j].z; acc[1][3] += a1v[j] * w[j].w;
            }
        }
        __syncthreads();
    }

    // xenc -> LDS (reuse xa)
    {
        float eb[4];
        #pragma unroll
        for (int j = 0; j < 4; j++) eb[j] = enc_b[tx4 + j];
        #pragma unroll
        for (int j = 0; j < 4; j++) {
            xa[ty][tx4 + j]      = acc[0][j] + eb[j];
            xa[ty + 16][tx4 + j] = acc[1][j] + eb[j];
        }
    }
    __syncthreads();

    // epilogue: thread (t = tid>>3, e = tid&7)
    const int t = tid >> 3;
    const int e = tid & 7;
    float logit = sw_b[e];
    #pragma unroll 16
    for (int r = 0; r < RDIM; r++)
        logit += xa[t][r] * sws[r * NEXP + e];

    // 8-lane argmax (first-max tie rule) + softmax denominator
    float m = logit; int am = e;
    #pragma unroll
    for (int d = 4; d >= 1; d >>= 1) {
        float om = __shfl_xor(m, d, 8);
        int oam  = __shfl_xor(am, d, 8);
        if (om > m || (om == m && oam < am)) { m = om; am = oam; }
    }
    float s = expf(logit - m);
    #pragma unroll
    for (int d = 1; d <= 4; d <<= 1) s += __shfl_xor(s, d, 8);

    int lp = 0;
    if (e == 0) {
        pmax[tok0 + t] = 1.0f / s;
        lp = atomicAdd(&lcnt[am], 1);
    }
    __syncthreads();
    if (tid < NEXP) gbase[tid] = atomicAdd(&counts[tid * 32], lcnt[tid]);
    __syncthreads();
    if (e == 0) lists[am * NTOK + gbase[am] + lp] = tok0 + t;
}

// ---------------------------------------------------------------------------
// mm1: h[tok] = gelu(x[tok] @ w1[e] + b1[e]) for gathered 32-token tiles.
// grid (8, 64) persistent.
// ---------------------------------------------------------------------------
__global__ __launch_bounds__(256) void mm1_kernel(
    const float* __restrict__ x, const float* __restrict__ w1,
    const float* __restrict__ b1, const int* __restrict__ counts,
    const int* __restrict__ lists, float* __restrict__ hws)
{
    __shared__ __align__(16) float xa[32][68];
    __shared__ __align__(16) float wb[64][68];
    __shared__ int tok_s[32];

    const int tid = threadIdx.x;
    const int e = blockIdx.x;
    const int cnt = counts[e * 32];
    const int ty = tid >> 4, tx = tid & 15, tx4 = tx * 4;

    for (int tile = blockIdx.y; tile * 32 < cnt; tile += 64) {
        const int base = tile * 32;
        const int nt = min(32, cnt - base);
        if (tid < 32) tok_s[tid] = lists[e * NTOK + base + min(tid, nt - 1)];
        __syncthreads();

        float acc[2][4] = {};
        for (int k0 = 0; k0 < HDIM; k0 += 64) {
            #pragma unroll
            for (int it = 0; it < 2; it++) {
                int idx = it * 256 + tid;
                int r = idx >> 4, c4 = (idx & 15) * 4;
                *(float4*)&xa[r][c4] = *(const float4*)(x + (size_t)tok_s[r] * HDIM + k0 + c4);
            }
            #pragma unroll
            for (int it = 0; it < 4; it++) {
                int off = it * 1024 + tid * 4;
                *(float4*)&wb[off >> 6][off & 63] =
                    *(const float4*)(w1 + ((size_t)e * HDIM + k0) * RDIM + off);
            }
            __syncthreads();
            #pragma unroll
            for (int kk = 0; kk < 64; kk += 4) {
                float4 a0 = *(float4*)&xa[ty][kk];
                float4 a1 = *(float4*)&xa[ty + 16][kk];
                float4 w[4];
                #pragma unroll
                for (int j = 0; j < 4; j++) w[j] = *(float4*)&wb[kk + j][tx4];
                float a0v[4] = {a0.x, a0.y, a0.z, a0.w};
                float a1v[4] = {a1.x, a1.y, a1.z, a1.w};
                #pragma unroll
                for (int j = 0; j < 4; j++) {
                    acc[0][0] += a0v[j] * w[j].x; acc[0][1] += a0v[j] * w[j].y;
                    acc[0][2] += a0v[j] * w[j].z; acc[0][3] += a0v[j] * w[j].w;
                    acc[1][0] += a1v[j] * w[j].x; acc[1][1] += a1v[j] * w[j].y;
                    acc[1][2] += a1v[j] * w[j].z; acc[1][3] += a1v[j] * w[j].w;
                }
            }
            __syncthreads();
        }

        float4 b1v = *(const float4*)(b1 + e * RDIM + tx4);
        if (ty < nt) {
            float4 o;
            o.x = gelu_exact(acc[0][0] + b1v.x); o.y = gelu_exact(acc[0][1] + b1v.y);
            o.z = gelu_exact(acc[0][2] + b1v.z); o.w = gelu_exact(acc[0][3] + b1v.w);
            *(float4*)(hws + (size_t)tok_s[ty] * RDIM + tx4) = o;
        }
        if (ty + 16 < nt) {
            float4 o;
            o.x = gelu_exact(acc[1][0] + b1v.x); o.y = gelu_exact(acc[1][1] + b1v.y);
            o.z = gelu_exact(acc[1][2] + b1v.z); o.w = gelu_exact(acc[1][3] + b1v.w);
            *(float4*)(hws + (size_t)tok_s[ty + 16] * RDIM + tx4) = o;
        }
        __syncthreads();   // tok_s reused next tile
    }
}

// ---------------------------------------------------------------------------
// mm2: out[tok] = (h[tok] @ w2[e] + b2[e]) * pmax[tok].
// grid (8, 32, 6): 64-token m-tiles (persistent, stride 32) x 128-col n-tiles.
// w2 tile staged once per block.
// ---------------------------------------------------------------------------
__global__ __launch_bounds__(256) void mm2_kernel(
    const float* __restrict__ hws, const float* __restrict__ w2,
    const float* __restrict__ b2, const float* __restrict__ pmax,
    const int* __restrict__ counts, const int* __restrict__ lists,
    float* __restrict__ out)
{
    __shared__ __align__(16) float hs[64][68];
    __shared__ __align__(16) float ws[64][132];
    __shared__ int tok_s[64];
    __shared__ float pm_s[64];

    const int tid = threadIdx.x;
    const int e = blockIdx.x;
    const int n0 = blockIdx.z * 128;
    const int cnt = counts[e * 32];
    const int ty = tid >> 4, tx = tid & 15, tx4 = tx * 4, ty4 = ty * 4;

    // stage w2 tile (e, n0) once
    #pragma unroll
    for (int it = 0; it < 8; it++) {
        int idx = it * 256 + tid;
        int r = idx >> 5, c4 = (idx & 31) * 4;
        *(float4*)&ws[r][c4] = *(const float4*)(w2 + ((size_t)e * RDIM + r) * HDIM + n0 + c4);
    }
    const float4 b2l = *(const float4*)(b2 + (size_t)e * HDIM + n0 + tx4);
    const float4 b2h = *(const float4*)(b2 + (size_t)e * HDIM + n0 + 64 + tx4);

    for (int mt = blockIdx.y; mt * 64 < cnt; mt += 32) {
        const int base = mt * 64;
        const int nt = min(64, cnt - base);
        __syncthreads();
        if (tid < 64) {
            int tk = lists[e * NTOK + base + min(tid, nt - 1)];
            tok_s[tid] = tk;
            pm_s[tid] = pmax[tk];
        }
        __syncthreads();
        #pragma unroll
        for (int it = 0; it < 4; it++) {
            int idx = it * 256 + tid;
            int r = idx >> 4, c4 = (idx & 15) * 4;
            *(float4*)&hs[r][c4] = *(const float4*)(hws + (size_t)tok_s[r] * RDIM + c4);
        }
        __syncthreads();

        float acc[4][8] = {};
        #pragma unroll
        for (int kk = 0; kk < 64; kk += 4) {
            float4 bl[4], bh[4];
            #pragma unroll
            for (int j = 0; j < 4; j++) {
                bl[j] = *(float4*)&ws[kk + j][tx4];
                bh[j] = *(float4*)&ws[kk + j][64 + tx4];
            }
            #pragma unroll
            for (int i = 0; i < 4; i++) {
                float4 av = *(float4*)&hs[ty4 + i][kk];
                float a[4] = {av.x, av.y, av.z, av.w};
                #pragma unroll
                for (int j = 0; j < 4; j++) {
                    acc[i][0] += a[j] * bl[j].x; acc[i][1] += a[j] * bl[j].y;
                    acc[i][2] += a[j] * bl[j].z; acc[i][3] += a[j] * bl[j].w;
                    acc[i][4] += a[j] * bh[j].x; acc[i][5] += a[j] * bh[j].y;
                    acc[i][6] += a[j] * bh[j].z; acc[i][7] += a[j] * bh[j].w;
                }
            }
        }

        #pragma unroll
        for (int i = 0; i < 4; i++) {
            int slot = ty4 + i;
            if (slot < nt) {
                int tk = tok_s[slot];
                float pm = pm_s[slot];
                float4 o;
                o.x = (acc[i][0] + b2l.x) * pm; o.y = (acc[i][1] + b2l.y) * pm;
                o.z = (acc[i][2] + b2l.z) * pm; o.w = (acc[i][3] + b2l.w) * pm;
                *(float4*)(out + (size_t)tk * HDIM + n0 + tx4) = o;
                float4 o2;
                o2.x = (acc[i][4] + b2h.x) * pm; o2.y = (acc[i][5] + b2h.y) * pm;
                o2.z = (acc[i][6] + b2h.z) * pm; o2.w = (acc[i][7] + b2h.w) * pm;
                *(float4*)(out + (size_t)tk * HDIM + n0 + 64 + tx4) = o2;
            }
        }
    }
}

extern "C" void kernel_launch(void* const* d_in, const int* in_sizes, int n_in,
                              void* d_out, int out_size, void* d_ws, size_t ws_size,
                              hipStream_t stream) {
    const float* x     = (const float*)d_in[0];
    const float* enc_w = (const float*)d_in[1];
    const float* enc_b = (const float*)d_in[2];
    const float* sw_w  = (const float*)d_in[3];
    const float* sw_b  = (const float*)d_in[4];
    const float* w1    = (const float*)d_in[5];
    const float* b1    = (const float*)d_in[6];
    const float* w2    = (const float*)d_in[7];
    const float* b2    = (const float*)d_in[8];
    float* out = (float*)d_out;

    // ws layout: [0,1KB) counts (8 ints, 128B stride); [1KB,+64KB) pmax;
    //            [+512KB) lists; [+4MB) hws. Total ~4.78 MB.
    int*   counts = (int*)d_ws;
    float* pmax   = (float*)((char*)d_ws + 1024);
    int*   lists  = (int*)((char*)d_ws + 1024 + 65536);
    float* hws    = (float*)((char*)d_ws + 1024 + 65536 + 524288);

    hipMemsetAsync(d_ws, 0, 1024, stream);

    hipLaunchKernelGGL(router_kernel, dim3(NTOK / 32), dim3(256), 0, stream,
                       x, enc_w, enc_b, sw_w, sw_b, pmax, counts, lists);
    hipLaunchKernelGGL(mm1_kernel, dim3(NEXP, 64), dim3(256), 0, stream,
                       x, w1, b1, counts, lists, hws);
    hipLaunchKernelGGL(mm2_kernel, dim3(NEXP, 32, 6), dim3(256), 0, stream,
                       hws, w2, b2, pmax, counts, lists, out);
}

// Round 3
// 300.785 us; speedup vs baseline: 2.8482x; 2.8482x over previous
//
#include <hip/hip_runtime.h>
#include <math.h>

#define HDIM 768
#define RDIM 64
#define NEXP 8
#define NTOK 16384

__device__ __forceinline__ float gelu_exact(float v) {
    return 0.5f * v * (1.0f + erff(v * 0.70710678118654752440f));
}

// ---------------------------------------------------------------------------
// Router: 32-token tile per block (512 blocks). xenc = x@enc_w+enc_b (K=768),
// epilogue over all 256 threads (32 tok x 8 exp), shuffle argmax/softmax,
// block-aggregated routing atomics.
// ---------------------------------------------------------------------------
__global__ __launch_bounds__(256) void router_kernel(
    const float* __restrict__ x, const float* __restrict__ enc_w,
    const float* __restrict__ enc_b, const float* __restrict__ sw_w,
    const float* __restrict__ sw_b, float* __restrict__ pmax,
    int* __restrict__ counts, int* __restrict__ lists)
{
    __shared__ __align__(16) float xa[32][68];
    __shared__ __align__(16) float wb[64][68];
    __shared__ __align__(16) float sws[512];    // sw_w [64][8]
    __shared__ int lcnt[NEXP], gbase[NEXP];

    const int tid = threadIdx.x;
    const int tok0 = blockIdx.x * 32;
    const int ty = tid >> 4, tx = tid & 15, tx4 = tx * 4;

    if (tid < 128) ((float4*)sws)[tid] = ((const float4*)sw_w)[tid];
    if (tid < NEXP) lcnt[tid] = 0;

    float acc[2][4] = {};

    for (int k0 = 0; k0 < HDIM; k0 += 64) {
        #pragma unroll
        for (int it = 0; it < 2; it++) {
            int idx = it * 256 + tid;
            int r = idx >> 4, c4 = (idx & 15) * 4;
            *(float4*)&xa[r][c4] = *(const float4*)(x + (size_t)(tok0 + r) * HDIM + k0 + c4);
        }
        #pragma unroll
        for (int it = 0; it < 4; it++) {
            int off = it * 1024 + tid * 4;
            *(float4*)&wb[off >> 6][off & 63] = *(const float4*)(enc_w + (size_t)k0 * RDIM + off);
        }
        __syncthreads();
        #pragma unroll
        for (int kk = 0; kk < 64; kk += 4) {
            float4 a0 = *(float4*)&xa[ty][kk];
            float4 a1 = *(float4*)&xa[ty + 16][kk];
            float4 w[4];
            #pragma unroll
            for (int j = 0; j < 4; j++) w[j] = *(float4*)&wb[kk + j][tx4];
            float a0v[4] = {a0.x, a0.y, a0.z, a0.w};
            float a1v[4] = {a1.x, a1.y, a1.z, a1.w};
            #pragma unroll
            for (int j = 0; j < 4; j++) {
                acc[0][0] += a0v[j] * w[j].x; acc[0][1] += a0v[j] * w[j].y;
                acc[0][2] += a0v[j] * w[j].z; acc[0][3] += a0v[j] * w[j].w;
                acc[1][0] += a1v[j] * w[j].x; acc[1][1] += a1v[j] * w[j].y;
                acc[1][2] += a1v[j] * w[j].z; acc[1][3] += a1v[j] * w[j].w;
            }
        }
        __syncthreads();
    }

    // xenc -> LDS (reuse xa)
    {
        float eb[4];
        #pragma unroll
        for (int j = 0; j < 4; j++) eb[j] = enc_b[tx4 + j];
        #pragma unroll
        for (int j = 0; j < 4; j++) {
            xa[ty][tx4 + j]      = acc[0][j] + eb[j];
            xa[ty + 16][tx4 + j] = acc[1][j] + eb[j];
        }
    }
    __syncthreads();

    // epilogue: thread (t = tid>>3, e = tid&7)
    const int t = tid >> 3;
    const int e = tid & 7;
    float logit = sw_b[e];
    #pragma unroll 16
    for (int r = 0; r < RDIM; r++)
        logit += xa[t][r] * sws[r * NEXP + e];

    // 8-lane argmax (first-max tie rule) + softmax denominator
    float m = logit; int am = e;
    #pragma unroll
    for (int d = 4; d >= 1; d >>= 1) {
        float om = __shfl_xor(m, d, 8);
        int oam  = __shfl_xor(am, d, 8);
        if (om > m || (om == m && oam < am)) { m = om; am = oam; }
    }
    float s = expf(logit - m);
    #pragma unroll
    for (int d = 1; d <= 4; d <<= 1) s += __shfl_xor(s, d, 8);

    int lp = 0;
    if (e == 0) {
        pmax[tok0 + t] = 1.0f / s;
        lp = atomicAdd(&lcnt[am], 1);
    }
    __syncthreads();
    if (tid < NEXP) gbase[tid] = atomicAdd(&counts[tid * 32], lcnt[tid]);
    __syncthreads();
    if (e == 0) lists[am * NTOK + gbase[am] + lp] = tok0 + t;
}

// ---------------------------------------------------------------------------
// mm1: h[tok] = gelu(x[tok] @ w1[e] + b1[e]) for gathered 32-token tiles.
// grid (8, 64) persistent.
// ---------------------------------------------------------------------------
__global__ __launch_bounds__(256) void mm1_kernel(
    const float* __restrict__ x, const float* __restrict__ w1,
    const float* __restrict__ b1, const int* __restrict__ counts,
    const int* __restrict__ lists, float* __restrict__ hws)
{
    __shared__ __align__(16) float xa[32][68];
    __shared__ __align__(16) float wb[64][68];
    __shared__ int tok_s[32];

    const int tid = threadIdx.x;
    const int e = blockIdx.x;
    const int cnt = counts[e * 32];
    const int ty = tid >> 4, tx = tid & 15, tx4 = tx * 4;

    for (int tile = blockIdx.y; tile * 32 < cnt; tile += 64) {
        const int base = tile * 32;
        const int nt = min(32, cnt - base);
        if (tid < 32) tok_s[tid] = lists[e * NTOK + base + min(tid, nt - 1)];
        __syncthreads();

        float acc[2][4] = {};
        for (int k0 = 0; k0 < HDIM; k0 += 64) {
            #pragma unroll
            for (int it = 0; it < 2; it++) {
                int idx = it * 256 + tid;
                int r = idx >> 4, c4 = (idx & 15) * 4;
                *(float4*)&xa[r][c4] = *(const float4*)(x + (size_t)tok_s[r] * HDIM + k0 + c4);
            }
            #pragma unroll
            for (int it = 0; it < 4; it++) {
                int off = it * 1024 + tid * 4;
                *(float4*)&wb[off >> 6][off & 63] =
                    *(const float4*)(w1 + ((size_t)e * HDIM + k0) * RDIM + off);
            }
            __syncthreads();
            #pragma unroll
            for (int kk = 0; kk < 64; kk += 4) {
                float4 a0 = *(float4*)&xa[ty][kk];
                float4 a1 = *(float4*)&xa[ty + 16][kk];
                float4 w[4];
                #pragma unroll
                for (int j = 0; j < 4; j++) w[j] = *(float4*)&wb[kk + j][tx4];
                float a0v[4] = {a0.x, a0.y, a0.z, a0.w};
                float a1v[4] = {a1.x, a1.y, a1.z, a1.w};
                #pragma unroll
                for (int j = 0; j < 4; j++) {
                    acc[0][0] += a0v[j] * w[j].x; acc[0][1] += a0v[j] * w[j].y;
                    acc[0][2] += a0v[j] * w[j].z; acc[0][3] += a0v[j] * w[j].w;
                    acc[1][0] += a1v[j] * w[j].x; acc[1][1] += a1v[j] * w[j].y;
                    acc[1][2] += a1v[j] * w[j].z; acc[1][3] += a1v[j] * w[j].w;
                }
            }
            __syncthreads();
        }

        float4 b1v = *(const float4*)(b1 + e * RDIM + tx4);
        if (ty < nt) {
            float4 o;
            o.x = gelu_exact(acc[0][0] + b1v.x); o.y = gelu_exact(acc[0][1] + b1v.y);
            o.z = gelu_exact(acc[0][2] + b1v.z); o.w = gelu_exact(acc[0][3] + b1v.w);
            *(float4*)(hws + (size_t)tok_s[ty] * RDIM + tx4) = o;
        }
        if (ty + 16 < nt) {
            float4 o;
            o.x = gelu_exact(acc[1][0] + b1v.x); o.y = gelu_exact(acc[1][1] + b1v.y);
            o.z = gelu_exact(acc[1][2] + b1v.z); o.w = gelu_exact(acc[1][3] + b1v.w);
            *(float4*)(hws + (size_t)tok_s[ty + 16] * RDIM + tx4) = o;
        }
        __syncthreads();   // tok_s reused next tile
    }
}

// ---------------------------------------------------------------------------
// mm2: out[tok] = (h[tok] @ w2[e] + b2[e]) * pmax[tok].
// grid (8, 32, 12): 64-token m-tiles (persistent, stride 32) x 64-col n-tiles.
// acc[4][4] per thread (keeps VGPRs ~<100 — R2's acc[4][8] hit the 256 cap
// and spilled to scratch: 750 MB of HBM spill traffic). w2 tile staged once.
// ---------------------------------------------------------------------------
__global__ __launch_bounds__(256) void mm2_kernel(
    const float* __restrict__ hws, const float* __restrict__ w2,
    const float* __restrict__ b2, const float* __restrict__ pmax,
    const int* __restrict__ counts, const int* __restrict__ lists,
    float* __restrict__ out)
{
    __shared__ __align__(16) float hs[64][68];
    __shared__ __align__(16) float ws[64][68];
    __shared__ int tok_s[64];
    __shared__ float pm_s[64];

    const int tid = threadIdx.x;
    const int e = blockIdx.x;
    const int n0 = blockIdx.z * 64;
    const int cnt = counts[e * 32];
    const int ty = tid >> 4, tx = tid & 15, tx4 = tx * 4, ty4 = ty * 4;

    // stage w2 tile (e, n0): 64 r-rows x 64 cols
    #pragma unroll
    for (int it = 0; it < 4; it++) {
        int idx = it * 256 + tid;
        int r = idx >> 4, c4 = (idx & 15) * 4;
        *(float4*)&ws[r][c4] = *(const float4*)(w2 + ((size_t)e * RDIM + r) * HDIM + n0 + c4);
    }
    const float4 b2v = *(const float4*)(b2 + (size_t)e * HDIM + n0 + tx4);

    for (int mt = blockIdx.y; mt * 64 < cnt; mt += 32) {
        const int base = mt * 64;
        const int nt = min(64, cnt - base);
        __syncthreads();   // covers ws staging (1st iter) / prior-tile reads
        if (tid < 64) {
            int tk = lists[e * NTOK + base + min(tid, nt - 1)];
            tok_s[tid] = tk;
            pm_s[tid] = pmax[tk];
        }
        __syncthreads();
        #pragma unroll
        for (int it = 0; it < 4; it++) {
            int idx = it * 256 + tid;
            int r = idx >> 4, c4 = (idx & 15) * 4;
            *(float4*)&hs[r][c4] = *(const float4*)(hws + (size_t)tok_s[r] * RDIM + c4);
        }
        __syncthreads();

        float acc[4][4] = {};
        #pragma unroll
        for (int kk = 0; kk < 64; kk += 4) {
            float4 b[4];
            #pragma unroll
            for (int j = 0; j < 4; j++) b[j] = *(float4*)&ws[kk + j][tx4];
            #pragma unroll
            for (int i = 0; i < 4; i++) {
                float4 av = *(float4*)&hs[ty4 + i][kk];
                float a[4] = {av.x, av.y, av.z, av.w};
                #pragma unroll
                for (int j = 0; j < 4; j++) {
                    acc[i][0] += a[j] * b[j].x; acc[i][1] += a[j] * b[j].y;
                    acc[i][2] += a[j] * b[j].z; acc[i][3] += a[j] * b[j].w;
                }
            }
        }

        #pragma unroll
        for (int i = 0; i < 4; i++) {
            int slot = ty4 + i;
            if (slot < nt) {
                int tk = tok_s[slot];
                float pm = pm_s[slot];
                float4 o;
                o.x = (acc[i][0] + b2v.x) * pm; o.y = (acc[i][1] + b2v.y) * pm;
                o.z = (acc[i][2] + b2v.z) * pm; o.w = (acc[i][3] + b2v.w) * pm;
                *(float4*)(out + (size_t)tk * HDIM + n0 + tx4) = o;
            }
        }
    }
}

extern "C" void kernel_launch(void* const* d_in, const int* in_sizes, int n_in,
                              void* d_out, int out_size, void* d_ws, size_t ws_size,
                              hipStream_t stream) {
    const float* x     = (const float*)d_in[0];
    const float* enc_w = (const float*)d_in[1];
    const float* enc_b = (const float*)d_in[2];
    const float* sw_w  = (const float*)d_in[3];
    const float* sw_b  = (const float*)d_in[4];
    const float* w1    = (const float*)d_in[5];
    const float* b1    = (const float*)d_in[6];
    const float* w2    = (const float*)d_in[7];
    const float* b2    = (const float*)d_in[8];
    float* out = (float*)d_out;

    // ws layout: [0,1KB) counts (8 ints, 128B stride); [1KB,+64KB) pmax;
    //            [+512KB) lists; [+4MB) hws. Total ~4.78 MB.
    int*   counts = (int*)d_ws;
    float* pmax   = (float*)((char*)d_ws + 1024);
    int*   lists  = (int*)((char*)d_ws + 1024 + 65536);
    float* hws    = (float*)((char*)d_ws + 1024 + 65536 + 524288);

    hipMemsetAsync(d_ws, 0, 1024, stream);

    hipLaunchKernelGGL(router_kernel, dim3(NTOK / 32), dim3(256), 0, stream,
                       x, enc_w, enc_b, sw_w, sw_b, pmax, counts, lists);
    hipLaunchKernelGGL(mm1_kernel, dim3(NEXP, 64), dim3(256), 0, stream,
                       x, w1, b1, counts, lists, hws);
    hipLaunchKernelGGL(mm2_kernel, dim3(NEXP, 32, 12), dim3(256), 0, stream,
                       hws, w2, b2, pmax, counts, lists, out);
}

// Round 4
// 297.653 us; speedup vs baseline: 2.8781x; 1.0105x over previous
//
#include <hip/hip_runtime.h>
#include <math.h>

#define HDIM 768
#define RDIM 64
#define NEXP 8
#define NTOK 16384
#define KSPLIT 3
#define KCHUNK 256

__device__ __forceinline__ float gelu_exact(float v) {
    return 0.5f * v * (1.0f + erff(v * 0.70710678118654752440f));
}

// ---------------------------------------------------------------------------
// router_a: part[kz][tok][r] = x[tok, kz*256:(kz+1)*256] @ enc_w[chunk]
// grid (256, 3): 64-token tiles x K-chunks. Register-prefetch double buffer.
// ---------------------------------------------------------------------------
__global__ __launch_bounds__(256, 3) void router_a_kernel(
    const float* __restrict__ x, const float* __restrict__ enc_w,
    float* __restrict__ part)
{
    __shared__ __align__(16) float xa[64][68];
    __shared__ __align__(16) float wb[64][68];
    const int tid = threadIdx.x;
    const int tok0 = blockIdx.x * 64;
    const int kbase = blockIdx.y * KCHUNK;
    const int ty = tid >> 4, tx = tid & 15, tx4 = tx * 4, ty4 = ty * 4;

    float4 px[4], pw[4];
    #pragma unroll
    for (int it = 0; it < 4; it++) {
        px[it] = *(const float4*)(x + (size_t)(tok0 + it * 16 + ty) * HDIM + kbase + tx4);
        pw[it] = *(const float4*)(enc_w + (size_t)(kbase + it * 16 + ty) * RDIM + tx4);
    }

    float acc[4][4] = {};
    for (int k0 = 0; k0 < KCHUNK; k0 += 64) {
        #pragma unroll
        for (int it = 0; it < 4; it++) {
            *(float4*)&xa[it * 16 + ty][tx4] = px[it];
            *(float4*)&wb[it * 16 + ty][tx4] = pw[it];
        }
        __syncthreads();
        if (k0 + 64 < KCHUNK) {
            #pragma unroll
            for (int it = 0; it < 4; it++) {
                px[it] = *(const float4*)(x + (size_t)(tok0 + it * 16 + ty) * HDIM + kbase + k0 + 64 + tx4);
                pw[it] = *(const float4*)(enc_w + (size_t)(kbase + k0 + 64 + it * 16 + ty) * RDIM + tx4);
            }
        }
        #pragma unroll 2
        for (int kk = 0; kk < 64; kk += 4) {
            float4 b[4];
            #pragma unroll
            for (int j = 0; j < 4; j++) b[j] = *(float4*)&wb[kk + j][tx4];
            #pragma unroll
            for (int i = 0; i < 4; i++) {
                float4 av = *(float4*)&xa[ty4 + i][kk];
                float a_[4] = {av.x, av.y, av.z, av.w};
                #pragma unroll
                for (int j = 0; j < 4; j++) {
                    acc[i][0] += a_[j] * b[j].x; acc[i][1] += a_[j] * b[j].y;
                    acc[i][2] += a_[j] * b[j].z; acc[i][3] += a_[j] * b[j].w;
                }
            }
        }
        __syncthreads();
    }

    const size_t zb = (size_t)blockIdx.y * NTOK;
    #pragma unroll
    for (int i = 0; i < 4; i++)
        *(float4*)(part + (zb + tok0 + ty4 + i) * RDIM + tx4) = *(float4*)&acc[i][0];
}

// ---------------------------------------------------------------------------
// router_b: xenc = sum(part) + enc_b; logits/softmax/argmax; pmax + lists.
// grid 256 x 64 tokens.
// ---------------------------------------------------------------------------
__global__ __launch_bounds__(256, 3) void router_b_kernel(
    const float* __restrict__ part, const float* __restrict__ enc_b,
    const float* __restrict__ sw_w, const float* __restrict__ sw_b,
    float* __restrict__ pmax, int* __restrict__ counts, int* __restrict__ lists)
{
    __shared__ __align__(16) float xe[64][68];
    __shared__ __align__(16) float sws[512];
    __shared__ int lcnt[NEXP], gbase[NEXP];

    const int tid = threadIdx.x;
    const int tok0 = blockIdx.x * 64;
    const int ty = tid >> 4, tx = tid & 15, tx4 = tx * 4;

    if (tid < 128) ((float4*)sws)[tid] = ((const float4*)sw_w)[tid];
    if (tid < NEXP) lcnt[tid] = 0;

    {
        float4 eb = *(const float4*)(enc_b + tx4);
        #pragma unroll
        for (int it = 0; it < 4; it++) {
            int r = it * 16 + ty;
            float4 p0 = *(const float4*)(part + ((size_t)0 * NTOK + tok0 + r) * RDIM + tx4);
            float4 p1 = *(const float4*)(part + ((size_t)1 * NTOK + tok0 + r) * RDIM + tx4);
            float4 p2 = *(const float4*)(part + ((size_t)2 * NTOK + tok0 + r) * RDIM + tx4);
            float4 v;
            v.x = p0.x + p1.x + p2.x + eb.x; v.y = p0.y + p1.y + p2.y + eb.y;
            v.z = p0.z + p1.z + p2.z + eb.z; v.w = p0.w + p1.w + p2.w + eb.w;
            *(float4*)&xe[r][tx4] = v;
        }
    }
    __syncthreads();

    int amr[2], lpr[2];
    const int e = tid & 7;
    #pragma unroll
    for (int pass = 0; pass < 2; pass++) {
        const int t = (tid >> 3) + 32 * pass;
        float logit = sw_b[e];
        #pragma unroll 16
        for (int r = 0; r < RDIM; r++)
            logit += xe[t][r] * sws[r * NEXP + e];
        float m = logit; int am = e;
        #pragma unroll
        for (int d = 4; d >= 1; d >>= 1) {
            float om = __shfl_xor(m, d, 8);
            int oam  = __shfl_xor(am, d, 8);
            if (om > m || (om == m && oam < am)) { m = om; am = oam; }
        }
        float s = expf(logit - m);
        #pragma unroll
        for (int d = 1; d <= 4; d <<= 1) s += __shfl_xor(s, d, 8);
        amr[pass] = am; lpr[pass] = 0;
        if (e == 0) {
            pmax[tok0 + t] = 1.0f / s;
            lpr[pass] = atomicAdd(&lcnt[am], 1);
        }
    }
    __syncthreads();
    if (tid < NEXP) gbase[tid] = atomicAdd(&counts[tid * 32], lcnt[tid]);
    __syncthreads();
    if (e == 0) {
        #pragma unroll
        for (int pass = 0; pass < 2; pass++) {
            const int t = (tid >> 3) + 32 * pass;
            lists[amr[pass] * NTOK + gbase[amr[pass]] + lpr[pass]] = tok0 + t;
        }
    }
}

// ---------------------------------------------------------------------------
// mm1: part[kz][tok][r] = x[tok, chunk] @ w1[e][chunk] (gathered, partial K).
// grid (8, 32, 3) persistent over m-tiles. NOTE: overwrites router's part
// buffer (router_b already consumed it).
// ---------------------------------------------------------------------------
__global__ __launch_bounds__(256, 3) void mm1_kernel(
    const float* __restrict__ x, const float* __restrict__ w1,
    const int* __restrict__ counts, const int* __restrict__ lists,
    float* __restrict__ part)
{
    __shared__ __align__(16) float xa[64][68];
    __shared__ __align__(16) float wb[64][68];
    __shared__ int tok_s[64];

    const int tid = threadIdx.x;
    const int e = blockIdx.x;
    const int kbase = blockIdx.z * KCHUNK;
    const int cnt = counts[e * 32];
    const int ty = tid >> 4, tx = tid & 15, tx4 = tx * 4, ty4 = ty * 4;
    const size_t zb = (size_t)blockIdx.z * NTOK;

    for (int mt = blockIdx.y; mt * 64 < cnt; mt += 32) {
        const int base = mt * 64;
        const int nt_ = min(64, cnt - base);
        __syncthreads();
        if (tid < 64) tok_s[tid] = lists[e * NTOK + base + min(tid, nt_ - 1)];
        __syncthreads();

        const float* xrow[4];
        #pragma unroll
        for (int it = 0; it < 4; it++) xrow[it] = x + (size_t)tok_s[it * 16 + ty] * HDIM + kbase;

        float4 px[4], pw[4];
        #pragma unroll
        for (int it = 0; it < 4; it++) {
            px[it] = *(const float4*)(xrow[it] + tx4);
            pw[it] = *(const float4*)(w1 + ((size_t)e * HDIM + kbase + it * 16 + ty) * RDIM + tx4);
        }

        float acc[4][4] = {};
        for (int k0 = 0; k0 < KCHUNK; k0 += 64) {
            #pragma unroll
            for (int it = 0; it < 4; it++) {
                *(float4*)&xa[it * 16 + ty][tx4] = px[it];
                *(float4*)&wb[it * 16 + ty][tx4] = pw[it];
            }
            __syncthreads();
            if (k0 + 64 < KCHUNK) {
                #pragma unroll
                for (int it = 0; it < 4; it++) {
                    px[it] = *(const float4*)(xrow[it] + k0 + 64 + tx4);
                    pw[it] = *(const float4*)(w1 + ((size_t)e * HDIM + kbase + k0 + 64 + it * 16 + ty) * RDIM + tx4);
                }
            }
            #pragma unroll 2
            for (int kk = 0; kk < 64; kk += 4) {
                float4 b[4];
                #pragma unroll
                for (int j = 0; j < 4; j++) b[j] = *(float4*)&wb[kk + j][tx4];
                #pragma unroll
                for (int i = 0; i < 4; i++) {
                    float4 av = *(float4*)&xa[ty4 + i][kk];
                    float a_[4] = {av.x, av.y, av.z, av.w};
                    #pragma unroll
                    for (int j = 0; j < 4; j++) {
                        acc[i][0] += a_[j] * b[j].x; acc[i][1] += a_[j] * b[j].y;
                        acc[i][2] += a_[j] * b[j].z; acc[i][3] += a_[j] * b[j].w;
                    }
                }
            }
            __syncthreads();
        }

        #pragma unroll
        for (int i = 0; i < 4; i++) {
            int slot = ty4 + i;
            if (slot < nt_)
                *(float4*)(part + (zb + tok_s[slot]) * RDIM + tx4) = *(float4*)&acc[i][0];
        }
    }
}

// ---------------------------------------------------------------------------
// mm2: out[tok] = (gelu(sum(part)+b1) @ w2[e] + b2[e]) * pmax[tok].
// grid (8, 32, 3): m-tiles persistent x 4 n-tiles per z. hs staged once per
// m-tile, reused across n-tiles; w2 register-prefetch double buffer.
// ---------------------------------------------------------------------------
__global__ __launch_bounds__(256, 3) void mm2_kernel(
    const float* __restrict__ part, const float* __restrict__ w2,
    const float* __restrict__ b1, const float* __restrict__ b2,
    const float* __restrict__ pmax, const int* __restrict__ counts,
    const int* __restrict__ lists, float* __restrict__ out)
{
    __shared__ __align__(16) float hs[64][68];
    __shared__ __align__(16) float ws[64][68];
    __shared__ int tok_s[64];
    __shared__ float pm_s[64];

    const int tid = threadIdx.x;
    const int e = blockIdx.x;
    const int nbase = blockIdx.z * 4 * 64;
    const int cnt = counts[e * 32];
    const int ty = tid >> 4, tx = tid & 15, tx4 = tx * 4, ty4 = ty * 4;

    for (int mt = blockIdx.y; mt * 64 < cnt; mt += 32) {
        const int base = mt * 64;
        const int nt_ = min(64, cnt - base);
        __syncthreads();
        if (tid < 64) {
            int tk = lists[e * NTOK + base + min(tid, nt_ - 1)];
            tok_s[tid] = tk;
            pm_s[tid] = pmax[tk];
        }
        __syncthreads();

        // stage h = gelu(p0+p1+p2+b1) for the 64 gathered tokens
        {
            float4 b1v = *(const float4*)(b1 + e * RDIM + tx4);
            #pragma unroll
            for (int it = 0; it < 4; it++) {
                int tk = tok_s[it * 16 + ty];
                float4 p0 = *(const float4*)(part + ((size_t)0 * NTOK + tk) * RDIM + tx4);
                float4 p1 = *(const float4*)(part + ((size_t)1 * NTOK + tk) * RDIM + tx4);
                float4 p2 = *(const float4*)(part + ((size_t)2 * NTOK + tk) * RDIM + tx4);
                float4 h;
                h.x = gelu_exact(p0.x + p1.x + p2.x + b1v.x);
                h.y = gelu_exact(p0.y + p1.y + p2.y + b1v.y);
                h.z = gelu_exact(p0.z + p1.z + p2.z + b1v.z);
                h.w = gelu_exact(p0.w + p1.w + p2.w + b1v.w);
                *(float4*)&hs[it * 16 + ty][tx4] = h;
            }
        }

        float4 pw[4];
        #pragma unroll
        for (int it = 0; it < 4; it++)
            pw[it] = *(const float4*)(w2 + ((size_t)e * RDIM + it * 16 + ty) * HDIM + nbase + tx4);

        for (int ni = 0; ni < 4; ni++) {
            const int n0 = nbase + ni * 64;
            __syncthreads();   // ws (and hs on ni=0) free
            #pragma unroll
            for (int it = 0; it < 4; it++)
                *(float4*)&ws[it * 16 + ty][tx4] = pw[it];
            __syncthreads();
            if (ni < 3) {
                #pragma unroll
                for (int it = 0; it < 4; it++)
                    pw[it] = *(const float4*)(w2 + ((size_t)e * RDIM + it * 16 + ty) * HDIM + n0 + 64 + tx4);
            }

            float acc[4][4] = {};
            #pragma unroll 2
            for (int kk = 0; kk < 64; kk += 4) {
                float4 b[4];
                #pragma unroll
                for (int j = 0; j < 4; j++) b[j] = *(float4*)&ws[kk + j][tx4];
                #pragma unroll
                for (int i = 0; i < 4; i++) {
                    float4 av = *(float4*)&hs[ty4 + i][kk];
                    float a_[4] = {av.x, av.y, av.z, av.w};
                    #pragma unroll
                    for (int j = 0; j < 4; j++) {
                        acc[i][0] += a_[j] * b[j].x; acc[i][1] += a_[j] * b[j].y;
                        acc[i][2] += a_[j] * b[j].z; acc[i][3] += a_[j] * b[j].w;
                    }
                }
            }

            float4 b2v = *(const float4*)(b2 + (size_t)e * HDIM + n0 + tx4);
            #pragma unroll
            for (int i = 0; i < 4; i++) {
                int slot = ty4 + i;
                if (slot < nt_) {
                    int tk = tok_s[slot];
                    float pm = pm_s[slot];
                    float4 o;
                    o.x = (acc[i][0] + b2v.x) * pm; o.y = (acc[i][1] + b2v.y) * pm;
                    o.z = (acc[i][2] + b2v.z) * pm; o.w = (acc[i][3] + b2v.w) * pm;
                    *(float4*)(out + (size_t)tk * HDIM + n0 + tx4) = o;
                }
            }
        }
    }
}

extern "C" void kernel_launch(void* const* d_in, const int* in_sizes, int n_in,
                              void* d_out, int out_size, void* d_ws, size_t ws_size,
                              hipStream_t stream) {
    const float* x     = (const float*)d_in[0];
    const float* enc_w = (const float*)d_in[1];
    const float* enc_b = (const float*)d_in[2];
    const float* sw_w  = (const float*)d_in[3];
    const float* sw_b  = (const float*)d_in[4];
    const float* w1    = (const float*)d_in[5];
    const float* b1    = (const float*)d_in[6];
    const float* w2    = (const float*)d_in[7];
    const float* b2    = (const float*)d_in[8];
    float* out = (float*)d_out;

    // ws layout: [0,1K) counts; [1K,+64K) pmax; [+512K) lists;
    //            [+12.6M) part (shared by router partials then h partials).
    int*   counts = (int*)d_ws;
    float* pmax   = (float*)((char*)d_ws + 1024);
    int*   lists  = (int*)((char*)d_ws + 1024 + 65536);
    float* part   = (float*)((char*)d_ws + 1024 + 65536 + 524288);

    hipMemsetAsync(d_ws, 0, 1024, stream);

    hipLaunchKernelGGL(router_a_kernel, dim3(NTOK / 64, KSPLIT), dim3(256), 0, stream,
                       x, enc_w, part);
    hipLaunchKernelGGL(router_b_kernel, dim3(NTOK / 64), dim3(256), 0, stream,
                       part, enc_b, sw_w, sw_b, pmax, counts, lists);
    hipLaunchKernelGGL(mm1_kernel, dim3(NEXP, 32, KSPLIT), dim3(256), 0, stream,
                       x, w1, counts, lists, part);
    hipLaunchKernelGGL(mm2_kernel, dim3(NEXP, 32, KSPLIT), dim3(256), 0, stream,
                       part, w2, b1, b2, pmax, counts, lists, out);
}

// Round 5
// 241.842 us; speedup vs baseline: 3.5423x; 1.2308x over previous
//
#include <hip/hip_runtime.h>
#include <math.h>

#define HDIM 768
#define RDIM 64
#define NEXP 8
#define NTOK 16384
#define KSPLIT 3
#define KCHUNK 256

typedef _Float16 half8 __attribute__((ext_vector_type(8)));
typedef float float4_t __attribute__((ext_vector_type(4)));

__device__ __forceinline__ float gelu_exact(float v) {
    return 0.5f * v * (1.0f + erff(v * 0.70710678118654752440f));
}

// ---------------------------------------------------------------------------
// router_a: part[kz][tok][r] = x[tok, kz*256:(kz+1)*256] @ enc_w[chunk]
// (unchanged from R4 — fp32 mandatory: f16 logits would flip ~100 argmax
// routes vs the np reference -> 0.3 absmax fail)
// ---------------------------------------------------------------------------
__global__ __launch_bounds__(256, 3) void router_a_kernel(
    const float* __restrict__ x, const float* __restrict__ enc_w,
    float* __restrict__ part)
{
    __shared__ __align__(16) float xa[64][68];
    __shared__ __align__(16) float wb[64][68];
    const int tid = threadIdx.x;
    const int tok0 = blockIdx.x * 64;
    const int kbase = blockIdx.y * KCHUNK;
    const int ty = tid >> 4, tx = tid & 15, tx4 = tx * 4, ty4 = ty * 4;

    float4 px[4], pw[4];
    #pragma unroll
    for (int it = 0; it < 4; it++) {
        px[it] = *(const float4*)(x + (size_t)(tok0 + it * 16 + ty) * HDIM + kbase + tx4);
        pw[it] = *(const float4*)(enc_w + (size_t)(kbase + it * 16 + ty) * RDIM + tx4);
    }

    float acc[4][4] = {};
    for (int k0 = 0; k0 < KCHUNK; k0 += 64) {
        #pragma unroll
        for (int it = 0; it < 4; it++) {
            *(float4*)&xa[it * 16 + ty][tx4] = px[it];
            *(float4*)&wb[it * 16 + ty][tx4] = pw[it];
        }
        __syncthreads();
        if (k0 + 64 < KCHUNK) {
            #pragma unroll
            for (int it = 0; it < 4; it++) {
                px[it] = *(const float4*)(x + (size_t)(tok0 + it * 16 + ty) * HDIM + kbase + k0 + 64 + tx4);
                pw[it] = *(const float4*)(enc_w + (size_t)(kbase + k0 + 64 + it * 16 + ty) * RDIM + tx4);
            }
        }
        #pragma unroll 2
        for (int kk = 0; kk < 64; kk += 4) {
            float4 b[4];
            #pragma unroll
            for (int j = 0; j < 4; j++) b[j] = *(float4*)&wb[kk + j][tx4];
            #pragma unroll
            for (int i = 0; i < 4; i++) {
                float4 av = *(float4*)&xa[ty4 + i][kk];
                float a_[4] = {av.x, av.y, av.z, av.w};
                #pragma unroll
                for (int j = 0; j < 4; j++) {
                    acc[i][0] += a_[j] * b[j].x; acc[i][1] += a_[j] * b[j].y;
                    acc[i][2] += a_[j] * b[j].z; acc[i][3] += a_[j] * b[j].w;
                }
            }
        }
        __syncthreads();
    }

    const size_t zb = (size_t)blockIdx.y * NTOK;
    #pragma unroll
    for (int i = 0; i < 4; i++)
        *(float4*)(part + (zb + tok0 + ty4 + i) * RDIM + tx4) = *(float4*)&acc[i][0];
}

// ---------------------------------------------------------------------------
// router_b: xenc = sum(part) + enc_b; logits/softmax/argmax; pmax + lists.
// (unchanged from R4)
// ---------------------------------------------------------------------------
__global__ __launch_bounds__(256, 3) void router_b_kernel(
    const float* __restrict__ part, const float* __restrict__ enc_b,
    const float* __restrict__ sw_w, const float* __restrict__ sw_b,
    float* __restrict__ pmax, int* __restrict__ counts, int* __restrict__ lists)
{
    __shared__ __align__(16) float xe[64][68];
    __shared__ __align__(16) float sws[512];
    __shared__ int lcnt[NEXP], gbase[NEXP];

    const int tid = threadIdx.x;
    const int tok0 = blockIdx.x * 64;
    const int ty = tid >> 4, tx = tid & 15, tx4 = tx * 4;

    if (tid < 128) ((float4*)sws)[tid] = ((const float4*)sw_w)[tid];
    if (tid < NEXP) lcnt[tid] = 0;

    {
        float4 eb = *(const float4*)(enc_b + tx4);
        #pragma unroll
        for (int it = 0; it < 4; it++) {
            int r = it * 16 + ty;
            float4 p0 = *(const float4*)(part + ((size_t)0 * NTOK + tok0 + r) * RDIM + tx4);
            float4 p1 = *(const float4*)(part + ((size_t)1 * NTOK + tok0 + r) * RDIM + tx4);
            float4 p2 = *(const float4*)(part + ((size_t)2 * NTOK + tok0 + r) * RDIM + tx4);
            float4 v;
            v.x = p0.x + p1.x + p2.x + eb.x; v.y = p0.y + p1.y + p2.y + eb.y;
            v.z = p0.z + p1.z + p2.z + eb.z; v.w = p0.w + p1.w + p2.w + eb.w;
            *(float4*)&xe[r][tx4] = v;
        }
    }
    __syncthreads();

    int amr[2], lpr[2];
    const int e = tid & 7;
    #pragma unroll
    for (int pass = 0; pass < 2; pass++) {
        const int t = (tid >> 3) + 32 * pass;
        float logit = sw_b[e];
        #pragma unroll 16
        for (int r = 0; r < RDIM; r++)
            logit += xe[t][r] * sws[r * NEXP + e];
        float m = logit; int am = e;
        #pragma unroll
        for (int d = 4; d >= 1; d >>= 1) {
            float om = __shfl_xor(m, d, 8);
            int oam  = __shfl_xor(am, d, 8);
            if (om > m || (om == m && oam < am)) { m = om; am = oam; }
        }
        float s = expf(logit - m);
        #pragma unroll
        for (int d = 1; d <= 4; d <<= 1) s += __shfl_xor(s, d, 8);
        amr[pass] = am; lpr[pass] = 0;
        if (e == 0) {
            pmax[tok0 + t] = 1.0f / s;
            lpr[pass] = atomicAdd(&lcnt[am], 1);
        }
    }
    __syncthreads();
    if (tid < NEXP) gbase[tid] = atomicAdd(&counts[tid * 32], lcnt[tid]);
    __syncthreads();
    if (e == 0) {
        #pragma unroll
        for (int pass = 0; pass < 2; pass++) {
            const int t = (tid >> 3) + 32 * pass;
            lists[amr[pass] * NTOK + gbase[amr[pass]] + lpr[pass]] = tok0 + t;
        }
    }
}

// ---------------------------------------------------------------------------
// prep: w1t[e][r][k] = (f16)w1[e][k][r];  w2t[e][n][k] = (f16)w2[e][k][n].
// B-operand of mfma_f32_16x16x32_f16 wants [n][k] with k-contiguous 8-elem
// runs per lane. 1536 waves, coalesced reads (lane = n/r index).
// ---------------------------------------------------------------------------
__global__ __launch_bounds__(256) void prep_kernel(
    const float* __restrict__ w1, const float* __restrict__ w2,
    _Float16* __restrict__ w1t, _Float16* __restrict__ w2t)
{
    const int wid = blockIdx.x * 4 + (threadIdx.x >> 6);
    const int lane = threadIdx.x & 63;
    if (wid < 768) {
        // w1t: e = wid/96, k-octet = wid%96
        const int e = wid / 96, k0 = (wid % 96) * 8;
        float v[8];
        #pragma unroll
        for (int j = 0; j < 8; j++)
            v[j] = w1[((size_t)(e * HDIM + k0 + j)) * RDIM + lane];
        half8 o;
        #pragma unroll
        for (int j = 0; j < 8; j++) o[j] = (_Float16)v[j];
        *(half8*)(w1t + ((size_t)(e * RDIM + lane)) * HDIM + k0) = o;
    } else {
        // w2t: id = wid-768: e = id/96, rem: nblk = rem/8 (0..11), oct = rem%8
        const int id = wid - 768;
        const int e = id / 96, rem = id % 96;
        const int n = (rem >> 3) * 64 + lane, k0 = (rem & 7) * 8;
        float v[8];
        #pragma unroll
        for (int j = 0; j < 8; j++)
            v[j] = w2[((size_t)(e * RDIM + k0 + j)) * HDIM + n];
        half8 o;
        #pragma unroll
        for (int j = 0; j < 8; j++) o[j] = (_Float16)v[j];
        *(half8*)(w2t + ((size_t)(e * HDIM + n)) * RDIM + k0) = o;
    }
}

// ---------------------------------------------------------------------------
// mm1 (f16 MFMA, LDS-free, barrier-free): h[tok][r] = gelu(x@w1[e]+b1) f16.
// Each wave owns a 16-token strip x full R=64 (4 n-frags), K=768 streamed
// straight from global into fragments (A: x fp32->f16 cast; B: w1t direct).
// ~50 VGPR -> 8 waves/SIMD.
// ---------------------------------------------------------------------------
__global__ __launch_bounds__(256) void mm1_kernel(
    const float* __restrict__ x, const _Float16* __restrict__ w1t,
    const float* __restrict__ b1, const int* __restrict__ counts,
    const int* __restrict__ lists, _Float16* __restrict__ h)
{
    const int e = blockIdx.x;
    const int cnt = counts[e * 32];
    const int wv = threadIdx.x >> 6, lane = threadIdx.x & 63;
    const int q = lane >> 4, c = lane & 15;

    for (int st = blockIdx.y * 4 + wv; st * 16 < cnt; st += 512) {
        const int base = st * 16;
        const int nt = cnt - base;
        const int tA = lists[e * NTOK + base + min(c, nt - 1)];
        const float* xrow = x + (size_t)tA * HDIM;
        const _Float16* wbase = w1t + ((size_t)(e * RDIM + c)) * HDIM + q * 8;

        float4_t acc[4] = {{0,0,0,0},{0,0,0,0},{0,0,0,0},{0,0,0,0}};
        #pragma unroll 4
        for (int k0 = 0; k0 < HDIM; k0 += 32) {
            float4 u0 = *(const float4*)(xrow + k0 + q * 8);
            float4 u1 = *(const float4*)(xrow + k0 + q * 8 + 4);
            half8 a;
            a[0] = (_Float16)u0.x; a[1] = (_Float16)u0.y;
            a[2] = (_Float16)u0.z; a[3] = (_Float16)u0.w;
            a[4] = (_Float16)u1.x; a[5] = (_Float16)u1.y;
            a[6] = (_Float16)u1.z; a[7] = (_Float16)u1.w;
            #pragma unroll
            for (int nf = 0; nf < 4; nf++) {
                half8 b = *(const half8*)(wbase + (size_t)nf * 16 * HDIM + k0);
                acc[nf] = __builtin_amdgcn_mfma_f32_16x16x32_f16(a, b, acc[nf], 0, 0, 0);
            }
        }

        // C layout: col = c (r within frag), row = q*4 + i (token slot)
        #pragma unroll
        for (int i = 0; i < 4; i++) {
            const int row = q * 4 + i;
            if (row < nt) {
                const int tok = lists[e * NTOK + base + row];
                _Float16* hrow = h + (size_t)tok * RDIM;
                #pragma unroll
                for (int nf = 0; nf < 4; nf++) {
                    float v = acc[nf][i] + b1[e * RDIM + nf * 16 + c];
                    hrow[nf * 16 + c] = (_Float16)gelu_exact(v);
                }
            }
        }
    }
}

// ---------------------------------------------------------------------------
// mm2 (f16 MFMA, LDS-free, barrier-free): out = (h@w2[e]+b2)*pmax.
// Wave task = (16-token strip, 256-wide n-chunk). K=64 = 2 MFMA per n-frag.
// ---------------------------------------------------------------------------
__global__ __launch_bounds__(256) void mm2_kernel(
    const _Float16* __restrict__ h, const _Float16* __restrict__ w2t,
    const float* __restrict__ b2, const float* __restrict__ pmax,
    const int* __restrict__ counts, const int* __restrict__ lists,
    float* __restrict__ out)
{
    const int e = blockIdx.x;
    const int cnt = counts[e * 32];
    const int wv = threadIdx.x >> 6, lane = threadIdx.x & 63;
    const int q = lane >> 4, c = lane & 15;

    const int task = blockIdx.y * 4 + wv;   // 0..383
    const int nch = task % 3;
    const int sidx = task / 3;              // 0..127

    for (int st = sidx; st * 16 < cnt; st += 128) {
        const int base = st * 16;
        const int nt = cnt - base;
        const int tA = lists[e * NTOK + base + min(c, nt - 1)];
        half8 a0 = *(const half8*)(h + (size_t)tA * RDIM + q * 8);
        half8 a1 = *(const half8*)(h + (size_t)tA * RDIM + 32 + q * 8);

        int tokv[4]; float pm[4]; bool ok[4];
        #pragma unroll
        for (int i = 0; i < 4; i++) {
            const int row = q * 4 + i;
            ok[i] = row < nt;
            tokv[i] = lists[e * NTOK + base + min(row, nt - 1)];
            pm[i] = pmax[tokv[i]];
        }

        #pragma unroll 4
        for (int nf = 0; nf < 16; nf++) {
            const int n = nch * 256 + nf * 16 + c;
            const _Float16* wrow = w2t + ((size_t)(e * HDIM + n)) * RDIM;
            half8 b0 = *(const half8*)(wrow + q * 8);
            half8 b1v = *(const half8*)(wrow + 32 + q * 8);
            float4_t acc = {0, 0, 0, 0};
            acc = __builtin_amdgcn_mfma_f32_16x16x32_f16(a0, b0, acc, 0, 0, 0);
            acc = __builtin_amdgcn_mfma_f32_16x16x32_f16(a1, b1v, acc, 0, 0, 0);
            const float b2v = b2[e * HDIM + n];
            #pragma unroll
            for (int i = 0; i < 4; i++) {
                if (ok[i])
                    out[(size_t)tokv[i] * HDIM + n] = (acc[i] + b2v) * pm[i];
            }
        }
    }
}

extern "C" void kernel_launch(void* const* d_in, const int* in_sizes, int n_in,
                              void* d_out, int out_size, void* d_ws, size_t ws_size,
                              hipStream_t stream) {
    const float* x     = (const float*)d_in[0];
    const float* enc_w = (const float*)d_in[1];
    const float* enc_b = (const float*)d_in[2];
    const float* sw_w  = (const float*)d_in[3];
    const float* sw_b  = (const float*)d_in[4];
    const float* w1    = (const float*)d_in[5];
    const float* b1    = (const float*)d_in[6];
    const float* w2    = (const float*)d_in[7];
    const float* b2    = (const float*)d_in[8];
    float* out = (float*)d_out;

    // ws layout: [0,1K) counts; [1K,+64K) pmax; [+512K) lists; [+12.58M) part.
    // After router_b consumes part, its space is reused: w1t (768K f16),
    // w2t (768K f16), h (2M f16). Footprint identical to R3/R4 (13.2 MB).
    int*   counts = (int*)d_ws;
    float* pmax   = (float*)((char*)d_ws + 1024);
    int*   lists  = (int*)((char*)d_ws + 1024 + 65536);
    float* part   = (float*)((char*)d_ws + 1024 + 65536 + 524288);
    _Float16* w1t = (_Float16*)part;
    _Float16* w2t = (_Float16*)((char*)part + 786432);
    _Float16* h   = (_Float16*)((char*)part + 1572864);

    hipMemsetAsync(d_ws, 0, 1024, stream);

    hipLaunchKernelGGL(router_a_kernel, dim3(NTOK / 64, KSPLIT), dim3(256), 0, stream,
                       x, enc_w, part);
    hipLaunchKernelGGL(router_b_kernel, dim3(NTOK / 64), dim3(256), 0, stream,
                       part, enc_b, sw_w, sw_b, pmax, counts, lists);
    hipLaunchKernelGGL(prep_kernel, dim3(384), dim3(256), 0, stream,
                       w1, w2, w1t, w2t);
    hipLaunchKernelGGL(mm1_kernel, dim3(NEXP, 128), dim3(256), 0, stream,
                       x, w1t, b1, counts, lists, h);
    hipLaunchKernelGGL(mm2_kernel, dim3(NEXP, 96), dim3(256), 0, stream,
                       h, w2t, b2, pmax, counts, lists, out);
}

// Round 6
// 218.799 us; speedup vs baseline: 3.9154x; 1.1053x over previous
//
#include <hip/hip_runtime.h>
#include <math.h>

#define HDIM 768
#define RDIM 64
#define NEXP 8
#define NTOK 16384

typedef _Float16 half8 __attribute__((ext_vector_type(8)));
typedef float float4_t __attribute__((ext_vector_type(4)));

__device__ __forceinline__ float gelu_exact(float v) {
    return 0.5f * v * (1.0f + erff(v * 0.70710678118654752440f));
}

// ---------------------------------------------------------------------------
// prep: weight transposes/casts.
//   w1t[e][r][k]  = (f16)w1[e][k][r]                     (expert path, plain f16)
//   w2t[e][n][k]  = (f16)w2[e][k][n]
//   enc_hi/lo[r][k] = split-f16 of enc_w[k][r]           (router, hi/lo pair)
// ---------------------------------------------------------------------------
__global__ __launch_bounds__(256) void prep_kernel(
    const float* __restrict__ w1, const float* __restrict__ w2,
    const float* __restrict__ enc_w,
    _Float16* __restrict__ w1t, _Float16* __restrict__ w2t,
    _Float16* __restrict__ enc_hi, _Float16* __restrict__ enc_lo)
{
    const int wid = blockIdx.x * 4 + (threadIdx.x >> 6);
    const int lane = threadIdx.x & 63;
    if (wid < 768) {
        const int e = wid / 96, k0 = (wid % 96) * 8;
        half8 o;
        #pragma unroll
        for (int j = 0; j < 8; j++)
            o[j] = (_Float16)w1[((size_t)(e * HDIM + k0 + j)) * RDIM + lane];
        *(half8*)(w1t + ((size_t)(e * RDIM + lane)) * HDIM + k0) = o;
    } else if (wid < 1536) {
        const int id = wid - 768;
        const int e = id / 96, rem = id % 96;
        const int n = (rem >> 3) * 64 + lane, k0 = (rem & 7) * 8;
        half8 o;
        #pragma unroll
        for (int j = 0; j < 8; j++)
            o[j] = (_Float16)w2[((size_t)(e * RDIM + k0 + j)) * HDIM + n];
        *(half8*)(w2t + ((size_t)(e * HDIM + n)) * RDIM + k0) = o;
    } else if (wid < 1632) {
        // enc hi/lo: k-octet per wave, lane = r
        const int k0 = (wid - 1536) * 8;
        half8 hi, lo;
        #pragma unroll
        for (int j = 0; j < 8; j++) {
            float v = enc_w[(size_t)(k0 + j) * RDIM + lane];
            _Float16 h = (_Float16)v;
            hi[j] = h;
            lo[j] = (_Float16)(v - (float)h);
        }
        *(half8*)(enc_hi + (size_t)lane * HDIM + k0) = hi;
        *(half8*)(enc_lo + (size_t)lane * HDIM + k0) = lo;
    }
}

// ---------------------------------------------------------------------------
// router (fused, MFMA): xenc via split-f16 hi/lo (3 MFMAs -> ~1e-6 logit err,
// same band as fp32 reorder), then fp32 VALU epilogue:
// logits/softmax/argmax, block-aggregated routing atomics.
// Grid 256 x block 256 (4 waves x 16-token strips = 64 tokens/block).
// ---------------------------------------------------------------------------
__global__ __launch_bounds__(256) void router_kernel(
    const float* __restrict__ x,
    const _Float16* __restrict__ enc_hi, const _Float16* __restrict__ enc_lo,
    const float* __restrict__ enc_b, const float* __restrict__ sw_w,
    const float* __restrict__ sw_b, float* __restrict__ pmax,
    int* __restrict__ counts, int* __restrict__ lists)
{
    __shared__ __align__(16) float xe[64][68];
    __shared__ __align__(16) float sws[512];
    __shared__ int lcnt[NEXP], gbase[NEXP];

    const int tid = threadIdx.x;
    const int tok0 = blockIdx.x * 64;
    const int wv = tid >> 6, lane = tid & 63;
    const int q = lane >> 4, c = lane & 15;

    if (tid < 128) ((float4*)sws)[tid] = ((const float4*)sw_w)[tid];
    if (tid < NEXP) lcnt[tid] = 0;

    // ---- phase 1: xenc strip (16 tokens x 64 R), K=768, hi/lo split MFMA ----
    const float* xrow = x + (size_t)(tok0 + wv * 16 + c) * HDIM;
    const _Float16* ebase_hi = enc_hi + (size_t)c * HDIM + q * 8;
    const _Float16* ebase_lo = enc_lo + (size_t)c * HDIM + q * 8;

    float4_t acc[4] = {{0,0,0,0},{0,0,0,0},{0,0,0,0},{0,0,0,0}};
    #pragma unroll 2
    for (int k0 = 0; k0 < HDIM; k0 += 32) {
        float4 u0 = *(const float4*)(xrow + k0 + q * 8);
        float4 u1 = *(const float4*)(xrow + k0 + q * 8 + 4);
        float u[8] = {u0.x, u0.y, u0.z, u0.w, u1.x, u1.y, u1.z, u1.w};
        half8 ah, al;
        #pragma unroll
        for (int j = 0; j < 8; j++) {
            _Float16 h = (_Float16)u[j];
            ah[j] = h;
            al[j] = (_Float16)(u[j] - (float)h);
        }
        #pragma unroll
        for (int nf = 0; nf < 4; nf++) {
            half8 bh = *(const half8*)(ebase_hi + (size_t)nf * 16 * HDIM + k0);
            half8 bl = *(const half8*)(ebase_lo + (size_t)nf * 16 * HDIM + k0);
            acc[nf] = __builtin_amdgcn_mfma_f32_16x16x32_f16(ah, bh, acc[nf], 0, 0, 0);
            acc[nf] = __builtin_amdgcn_mfma_f32_16x16x32_f16(ah, bl, acc[nf], 0, 0, 0);
            acc[nf] = __builtin_amdgcn_mfma_f32_16x16x32_f16(al, bh, acc[nf], 0, 0, 0);
        }
    }

    // ---- phase 2: xenc + enc_b -> LDS (row = token slot, col = r) ----
    {
        float ebv[4];
        #pragma unroll
        for (int nf = 0; nf < 4; nf++) ebv[nf] = enc_b[nf * 16 + c];
        #pragma unroll
        for (int nf = 0; nf < 4; nf++)
            #pragma unroll
            for (int i = 0; i < 4; i++)
                xe[wv * 16 + q * 4 + i][nf * 16 + c] = acc[nf][i] + ebv[nf];
    }
    __syncthreads();

    // ---- phase 3: logits/softmax/argmax (fp32, proven router_b epilogue) ----
    int amr[2], lpr[2];
    const int e = tid & 7;
    #pragma unroll
    for (int pass = 0; pass < 2; pass++) {
        const int t = (tid >> 3) + 32 * pass;
        float logit = sw_b[e];
        #pragma unroll 16
        for (int r = 0; r < RDIM; r++)
            logit += xe[t][r] * sws[r * NEXP + e];
        float m = logit; int am = e;
        #pragma unroll
        for (int d = 4; d >= 1; d >>= 1) {
            float om = __shfl_xor(m, d, 8);
            int oam  = __shfl_xor(am, d, 8);
            if (om > m || (om == m && oam < am)) { m = om; am = oam; }
        }
        float s = expf(logit - m);
        #pragma unroll
        for (int d = 1; d <= 4; d <<= 1) s += __shfl_xor(s, d, 8);
        amr[pass] = am; lpr[pass] = 0;
        if (e == 0) {
            pmax[tok0 + t] = 1.0f / s;
            lpr[pass] = atomicAdd(&lcnt[am], 1);
        }
    }
    __syncthreads();
    if (tid < NEXP) gbase[tid] = atomicAdd(&counts[tid * 32], lcnt[tid]);
    __syncthreads();
    if (e == 0) {
        #pragma unroll
        for (int pass = 0; pass < 2; pass++) {
            const int t = (tid >> 3) + 32 * pass;
            lists[amr[pass] * NTOK + gbase[amr[pass]] + lpr[pass]] = tok0 + t;
        }
    }
}

// ---------------------------------------------------------------------------
// mm1 (f16 MFMA, LDS-free, barrier-free): h[tok][r] = gelu(x@w1[e]+b1) f16.
// (unchanged from R5)
// ---------------------------------------------------------------------------
__global__ __launch_bounds__(256) void mm1_kernel(
    const float* __restrict__ x, const _Float16* __restrict__ w1t,
    const float* __restrict__ b1, const int* __restrict__ counts,
    const int* __restrict__ lists, _Float16* __restrict__ h)
{
    const int e = blockIdx.x;
    const int cnt = counts[e * 32];
    const int wv = threadIdx.x >> 6, lane = threadIdx.x & 63;
    const int q = lane >> 4, c = lane & 15;

    for (int st = blockIdx.y * 4 + wv; st * 16 < cnt; st += 512) {
        const int base = st * 16;
        const int nt = cnt - base;
        const int tA = lists[e * NTOK + base + min(c, nt - 1)];
        const float* xrow = x + (size_t)tA * HDIM;
        const _Float16* wbase = w1t + ((size_t)(e * RDIM + c)) * HDIM + q * 8;

        float4_t acc[4] = {{0,0,0,0},{0,0,0,0},{0,0,0,0},{0,0,0,0}};
        #pragma unroll 4
        for (int k0 = 0; k0 < HDIM; k0 += 32) {
            float4 u0 = *(const float4*)(xrow + k0 + q * 8);
            float4 u1 = *(const float4*)(xrow + k0 + q * 8 + 4);
            half8 a;
            a[0] = (_Float16)u0.x; a[1] = (_Float16)u0.y;
            a[2] = (_Float16)u0.z; a[3] = (_Float16)u0.w;
            a[4] = (_Float16)u1.x; a[5] = (_Float16)u1.y;
            a[6] = (_Float16)u1.z; a[7] = (_Float16)u1.w;
            #pragma unroll
            for (int nf = 0; nf < 4; nf++) {
                half8 b = *(const half8*)(wbase + (size_t)nf * 16 * HDIM + k0);
                acc[nf] = __builtin_amdgcn_mfma_f32_16x16x32_f16(a, b, acc[nf], 0, 0, 0);
            }
        }

        #pragma unroll
        for (int i = 0; i < 4; i++) {
            const int row = q * 4 + i;
            if (row < nt) {
                const int tok = lists[e * NTOK + base + row];
                _Float16* hrow = h + (size_t)tok * RDIM;
                #pragma unroll
                for (int nf = 0; nf < 4; nf++) {
                    float v = acc[nf][i] + b1[e * RDIM + nf * 16 + c];
                    hrow[nf * 16 + c] = (_Float16)gelu_exact(v);
                }
            }
        }
    }
}

// ---------------------------------------------------------------------------
// mm2 (f16 MFMA, LDS-free, barrier-free): out = (h@w2[e]+b2)*pmax.
// (unchanged from R5)
// ---------------------------------------------------------------------------
__global__ __launch_bounds__(256) void mm2_kernel(
    const _Float16* __restrict__ h, const _Float16* __restrict__ w2t,
    const float* __restrict__ b2, const float* __restrict__ pmax,
    const int* __restrict__ counts, const int* __restrict__ lists,
    float* __restrict__ out)
{
    const int e = blockIdx.x;
    const int cnt = counts[e * 32];
    const int wv = threadIdx.x >> 6, lane = threadIdx.x & 63;
    const int q = lane >> 4, c = lane & 15;

    const int task = blockIdx.y * 4 + wv;   // 0..383
    const int nch = task % 3;
    const int sidx = task / 3;              // 0..127

    for (int st = sidx; st * 16 < cnt; st += 128) {
        const int base = st * 16;
        const int nt = cnt - base;
        const int tA = lists[e * NTOK + base + min(c, nt - 1)];
        half8 a0 = *(const half8*)(h + (size_t)tA * RDIM + q * 8);
        half8 a1 = *(const half8*)(h + (size_t)tA * RDIM + 32 + q * 8);

        int tokv[4]; float pm[4]; bool ok[4];
        #pragma unroll
        for (int i = 0; i < 4; i++) {
            const int row = q * 4 + i;
            ok[i] = row < nt;
            tokv[i] = lists[e * NTOK + base + min(row, nt - 1)];
            pm[i] = pmax[tokv[i]];
        }

        #pragma unroll 4
        for (int nf = 0; nf < 16; nf++) {
            const int n = nch * 256 + nf * 16 + c;
            const _Float16* wrow = w2t + ((size_t)(e * HDIM + n)) * RDIM;
            half8 b0 = *(const half8*)(wrow + q * 8);
            half8 b1v = *(const half8*)(wrow + 32 + q * 8);
            float4_t acc = {0, 0, 0, 0};
            acc = __builtin_amdgcn_mfma_f32_16x16x32_f16(a0, b0, acc, 0, 0, 0);
            acc = __builtin_amdgcn_mfma_f32_16x16x32_f16(a1, b1v, acc, 0, 0, 0);
            const float b2v = b2[e * HDIM + n];
            #pragma unroll
            for (int i = 0; i < 4; i++) {
                if (ok[i])
                    out[(size_t)tokv[i] * HDIM + n] = (acc[i] + b2v) * pm[i];
            }
        }
    }
}

extern "C" void kernel_launch(void* const* d_in, const int* in_sizes, int n_in,
                              void* d_out, int out_size, void* d_ws, size_t ws_size,
                              hipStream_t stream) {
    const float* x     = (const float*)d_in[0];
    const float* enc_w = (const float*)d_in[1];
    const float* enc_b = (const float*)d_in[2];
    const float* sw_w  = (const float*)d_in[3];
    const float* sw_b  = (const float*)d_in[4];
    const float* w1    = (const float*)d_in[5];
    const float* b1    = (const float*)d_in[6];
    const float* w2    = (const float*)d_in[7];
    const float* b2    = (const float*)d_in[8];
    float* out = (float*)d_out;

    // ws layout (~4.46 MB):
    //   [0,1K)       counts (8 ints, 128B stride)
    //   [1K,65K)     pmax 16384 f32
    //   [65K,577K)   lists 8*16384 i32
    //   [577K,..)    enc_hi (96K), enc_lo (96K), w1t (768K), w2t (768K), h (2M)
    char* p = (char*)d_ws;
    int*      counts = (int*)p;
    float*    pmax   = (float*)(p + 1024);
    int*      lists  = (int*)(p + 1024 + 65536);
    _Float16* enc_hi = (_Float16*)(p + 590848);
    _Float16* enc_lo = (_Float16*)(p + 590848 + 98304);
    _Float16* w1t    = (_Float16*)(p + 590848 + 196608);
    _Float16* w2t    = (_Float16*)(p + 590848 + 196608 + 786432);
    _Float16* h      = (_Float16*)(p + 590848 + 196608 + 1572864);

    hipMemsetAsync(d_ws, 0, 1024, stream);

    hipLaunchKernelGGL(prep_kernel, dim3(408), dim3(256), 0, stream,
                       w1, w2, enc_w, w1t, w2t, enc_hi, enc_lo);
    hipLaunchKernelGGL(router_kernel, dim3(NTOK / 64), dim3(256), 0, stream,
                       x, enc_hi, enc_lo, enc_b, sw_w, sw_b, pmax, counts, lists);
    hipLaunchKernelGGL(mm1_kernel, dim3(NEXP, 128), dim3(256), 0, stream,
                       x, w1t, b1, counts, lists, h);
    hipLaunchKernelGGL(mm2_kernel, dim3(NEXP, 96), dim3(256), 0, stream,
                       h, w2t, b2, pmax, counts, lists, out);
}